// Round 1
// baseline (1468.124 us; speedup 1.0000x reference)
//
#include <hip/hip_runtime.h>
#include <hip/hip_bf16.h>
#include <math.h>

// Problem constants (from reference)
#define BT_N 2048
#define H_N  2048
#define V_N  32000
#define IGNORE_INDEX (-100)

// Tiling
#define BMt 128
#define BNt 128
#define BKt 32
#define BKS 40               // padded LDS row stride in bf16 elems (80 B -> 2-way-free banks, 16B aligned)
#define NPART (V_N / 64)     // 500 partial chunks per row (one per 64-col wave chunk)

typedef __bf16 bf16x8 __attribute__((ext_vector_type(8)));
typedef __bf16 bf16x4 __attribute__((ext_vector_type(4)));
typedef float  f32x4  __attribute__((ext_vector_type(4)));

// Stage one [128 x 32] fp32 tile from global into LDS as bf16 (padded stride).
__device__ __forceinline__ void stage_tile(const float* __restrict__ src, int row0, int k0,
                                           __bf16* __restrict__ dst, int tid)
{
    int r = tid >> 3;                 // 0..31
    const int c = (tid & 7) << 2;     // 0,4,...,28
#pragma unroll
    for (int it = 0; it < 4; ++it, r += 32) {
        const float4 v = *reinterpret_cast<const float4*>(&src[(size_t)(row0 + r) * H_N + k0 + c]);
        bf16x4 p;
        p[0] = (__bf16)v.x; p[1] = (__bf16)v.y; p[2] = (__bf16)v.z; p[3] = (__bf16)v.w;
        *reinterpret_cast<bf16x4*>(&dst[r * BKS + c]) = p;
    }
}

// One NT-GEMM over full K into acc[4][4] (wave computes a 64x64 subtile).
__device__ __forceinline__ void gemm_bt(const float* __restrict__ A, const float* __restrict__ W,
                                        int m0, int n0,
                                        __bf16* __restrict__ Asm, __bf16* __restrict__ Wsm,
                                        int tid, int wr, int wc, int l15, int lk,
                                        f32x4 acc[4][4])
{
    for (int k0 = 0; k0 < H_N; k0 += BKt) {
        stage_tile(A, m0, k0, Asm, tid);
        stage_tile(W, n0, k0, Wsm, tid);
        __syncthreads();
        bf16x8 af[4], bfr[4];
#pragma unroll
        for (int i = 0; i < 4; ++i)
            af[i] = *reinterpret_cast<const bf16x8*>(&Asm[(wr + i * 16 + l15) * BKS + lk]);
#pragma unroll
        for (int j = 0; j < 4; ++j)
            bfr[j] = *reinterpret_cast<const bf16x8*>(&Wsm[(wc + j * 16 + l15) * BKS + lk]);
#pragma unroll
        for (int i = 0; i < 4; ++i)
#pragma unroll
            for (int j = 0; j < 4; ++j)
                acc[i][j] = __builtin_amdgcn_mfma_f32_16x16x32_bf16(af[i], bfr[j], acc[i][j], 0, 0, 0);
        __syncthreads();
    }
}

// Stage A: both GEMM tiles + in-register per-(row, 64-col-chunk) partial stats.
__global__ __launch_bounds__(256)
void flcs_stageA(const float* __restrict__ sIn, const float* __restrict__ sW,
                 const float* __restrict__ tIn, const float* __restrict__ tW,
                 const float* __restrict__ sB,  const float* __restrict__ tB,
                 const int* __restrict__ labels,
                 float* __restrict__ pMax, float* __restrict__ pSe,
                 float* __restrict__ pDot, float* __restrict__ pS2,
                 float* __restrict__ pT2,  float* __restrict__ sLab)
{
    __shared__ __bf16 Asm[BMt * BKS];
    __shared__ __bf16 Wsm[BNt * BKS];

    const int tid  = threadIdx.x;
    const int lane = tid & 63;
    const int wave = tid >> 6;
    const int wr   = (wave >> 1) * 64;   // wave row offset in tile
    const int wc   = (wave & 1) * 64;    // wave col offset in tile
    const int l15  = lane & 15;
    const int lsub = lane >> 4;          // 0..3
    const int lk   = lsub * 8;           // k offset of this lane's fragment
    const int m0   = blockIdx.x * BMt;
    const int n0   = blockIdx.y * BNt;

    f32x4 accS[4][4], accT[4][4];
    const f32x4 fz = {0.f, 0.f, 0.f, 0.f};
#pragma unroll
    for (int i = 0; i < 4; ++i)
#pragma unroll
        for (int j = 0; j < 4; ++j) { accS[i][j] = fz; accT[i][j] = fz; }

    gemm_bt(sIn, sW, m0, n0, Asm, Wsm, tid, wr, wc, l15, lk, accS);
    gemm_bt(tIn, tW, m0, n0, Asm, Wsm, tid, wr, wc, l15, lk, accT);

    // --- epilogue: per-row stats over this wave's 64 columns ---
    float sb[4], tb[4];
#pragma unroll
    for (int n = 0; n < 4; ++n) {
        sb[n] = sB[n0 + wc + n * 16 + l15];
        tb[n] = tB[n0 + wc + n * 16 + l15];
    }
    const int gcb = blockIdx.y * 2 + (wc >> 6);   // global 64-col chunk index, [0, 500)

#pragma unroll
    for (int i = 0; i < 4; ++i) {
#pragma unroll
        for (int q = 0; q < 4; ++q) {
            // this (i,q): 4 lane-groups hold 4 distinct rows; 16 lanes/group span 64 cols
            float s[4], t[4];
#pragma unroll
            for (int n = 0; n < 4; ++n) {
                s[n] = accS[i][n][q] + sb[n];
                t[n] = accT[i][n][q] + tb[n];
            }
            float mx = fmaxf(fmaxf(s[0], s[1]), fmaxf(s[2], s[3]));
#pragma unroll
            for (int d = 1; d <= 8; d <<= 1) mx = fmaxf(mx, __shfl_xor(mx, d));
            float se = 0.f, dot = 0.f, s2 = 0.f, t2 = 0.f;
#pragma unroll
            for (int n = 0; n < 4; ++n) {
                se  += __expf(s[n] - mx);
                dot += s[n] * t[n];
                s2  += s[n] * s[n];
                t2  += t[n] * t[n];
            }
#pragma unroll
            for (int d = 1; d <= 8; d <<= 1) {
                se  += __shfl_xor(se, d);
                dot += __shfl_xor(dot, d);
                s2  += __shfl_xor(s2, d);
                t2  += __shfl_xor(t2, d);
            }
            const int grow = m0 + wr + i * 16 + lsub * 4 + q;
            if (l15 == 0) {
                const size_t p = (size_t)grow * NPART + gcb;
                pMax[p] = mx; pSe[p] = se; pDot[p] = dot; pS2[p] = s2; pT2[p] = t2;
            }
            const int lab = labels[grow];
            const int rel = lab - (n0 + wc);
            if (rel >= 0 && rel < 64) {
#pragma unroll
                for (int n = 0; n < 4; ++n)
                    if (rel == n * 16 + l15) sLab[grow] = s[n];
            }
        }
    }
}

// Stage B: one wave per row; combine 500 chunk partials -> row nll & soft loss.
__global__ __launch_bounds__(256)
void flcs_stageB(const float* __restrict__ pMax, const float* __restrict__ pSe,
                 const float* __restrict__ pDot, const float* __restrict__ pS2,
                 const float* __restrict__ pT2,  const float* __restrict__ sLab,
                 float* __restrict__ rowNll, float* __restrict__ rowSoft)
{
    const int lane = threadIdx.x & 63;
    const int row  = blockIdx.x * 4 + (threadIdx.x >> 6);
    const size_t base = (size_t)row * NPART;

    float mx = -INFINITY;
    for (int i = lane; i < NPART; i += 64) mx = fmaxf(mx, pMax[base + i]);
#pragma unroll
    for (int d = 1; d <= 32; d <<= 1) mx = fmaxf(mx, __shfl_xor(mx, d));

    float se = 0.f, dot = 0.f, s2 = 0.f, t2 = 0.f;
    for (int i = lane; i < NPART; i += 64) {
        se  += pSe[base + i] * __expf(pMax[base + i] - mx);
        dot += pDot[base + i];
        s2  += pS2[base + i];
        t2  += pT2[base + i];
    }
#pragma unroll
    for (int d = 1; d <= 32; d <<= 1) {
        se  += __shfl_xor(se, d);
        dot += __shfl_xor(dot, d);
        s2  += __shfl_xor(s2, d);
        t2  += __shfl_xor(t2, d);
    }
    if (lane == 0) {
        const float lse = mx + logf(se);
        rowNll[row] = lse - sLab[row];
        const float ns = fmaxf(sqrtf(s2), 1e-12f);
        const float nt = fmaxf(sqrtf(t2), 1e-12f);
        rowSoft[row] = 0.5f * (1.f - dot / (ns * nt));   // BETA * (1 - cos)
    }
}

// Stage C: final deterministic reduction to the scalar loss.
__global__ __launch_bounds__(256)
void flcs_stageC(const float* __restrict__ rowNll, const float* __restrict__ rowSoft,
                 const int* __restrict__ labels, float* __restrict__ out)
{
    const int tid = threadIdx.x;
    float nll = 0.f, soft = 0.f, nv = 0.f;
    for (int i = tid; i < BT_N; i += 256) {
        if (labels[i] != IGNORE_INDEX) { nll += rowNll[i]; nv += 1.f; }
        soft += rowSoft[i];
    }
#pragma unroll
    for (int d = 1; d <= 32; d <<= 1) {
        nll  += __shfl_xor(nll, d);
        soft += __shfl_xor(soft, d);
        nv   += __shfl_xor(nv, d);
    }
    __shared__ float rN[4], rS[4], rV[4];
    const int w = tid >> 6;
    if ((tid & 63) == 0) { rN[w] = nll; rS[w] = soft; rV[w] = nv; }
    __syncthreads();
    if (tid == 0) {
        float N = 0.f, S = 0.f, Vv = 0.f;
        for (int k = 0; k < 4; ++k) { N += rN[k]; S += rS[k]; Vv += rV[k]; }
        out[0] = 0.5f * (N / fmaxf(Vv, 1.f)) + 0.5f * (S / (float)BT_N);
    }
}

extern "C" void kernel_launch(void* const* d_in, const int* in_sizes, int n_in,
                              void* d_out, int out_size, void* d_ws, size_t ws_size,
                              hipStream_t stream)
{
    const float* sIn    = (const float*)d_in[0];
    const float* sW     = (const float*)d_in[1];
    const float* tIn    = (const float*)d_in[2];
    const float* tW     = (const float*)d_in[3];
    const int*   labels = (const int*)d_in[4];
    const float* sB     = (const float*)d_in[5];
    const float* tB     = (const float*)d_in[6];
    float* out = (float*)d_out;

    float* pMax = (float*)d_ws;
    float* pSe  = pMax + (size_t)BT_N * NPART;
    float* pDot = pSe  + (size_t)BT_N * NPART;
    float* pS2  = pDot + (size_t)BT_N * NPART;
    float* pT2  = pS2  + (size_t)BT_N * NPART;
    float* sLab = pT2  + (size_t)BT_N * NPART;
    float* rowNll  = sLab + BT_N;
    float* rowSoft = rowNll + BT_N;

    flcs_stageA<<<dim3(BT_N / BMt, V_N / BNt), 256, 0, stream>>>(
        sIn, sW, tIn, tW, sB, tB, labels, pMax, pSe, pDot, pS2, pT2, sLab);
    flcs_stageB<<<BT_N / 4, 256, 0, stream>>>(pMax, pSe, pDot, pS2, pT2, sLab, rowNll, rowSoft);
    flcs_stageC<<<1, 256, 0, stream>>>(rowNll, rowSoft, labels, out);
}

// Round 2
// 998.461 us; speedup vs baseline: 1.4704x; 1.4704x over previous
//
#include <hip/hip_runtime.h>
#include <hip/hip_bf16.h>
#include <math.h>

// Problem constants (from reference)
#define BT_N 2048
#define H_N  2048
#define V_N  32000
#define IGNORE_INDEX (-100)

// Tiling
#define BMt 128
#define BNt 128
#define BKt 32
#define BKS 40               // fallback path: padded LDS stride
#define NPART (V_N / 64)     // 500 partial chunks per row

typedef __bf16 bf16x8 __attribute__((ext_vector_type(8)));
typedef __bf16 bf16x4 __attribute__((ext_vector_type(4)));
typedef float  f32x4  __attribute__((ext_vector_type(4)));

typedef const __attribute__((address_space(1))) void GVoid;
typedef __attribute__((address_space(3))) void LVoid;

__device__ __forceinline__ void gload_lds16(const __bf16* g, __bf16* l)
{
    __builtin_amdgcn_global_load_lds((GVoid*)g, (LVoid*)l, 16, 0, 0);
}

// ---------------------------------------------------------------- cast pass
__global__ __launch_bounds__(256)
void cast_f32_bf16(const float* __restrict__ src, __bf16* __restrict__ dst, int n8)
{
    int i = blockIdx.x * 256 + threadIdx.x;
    const int stride = gridDim.x * 256;
    for (; i < n8; i += stride) {
        const size_t b = (size_t)i * 8;
        const float4 a0 = *reinterpret_cast<const float4*>(&src[b]);
        const float4 a1 = *reinterpret_cast<const float4*>(&src[b + 4]);
        bf16x8 o;
        o[0] = (__bf16)a0.x; o[1] = (__bf16)a0.y; o[2] = (__bf16)a0.z; o[3] = (__bf16)a0.w;
        o[4] = (__bf16)a1.x; o[5] = (__bf16)a1.y; o[6] = (__bf16)a1.z; o[7] = (__bf16)a1.w;
        *reinterpret_cast<bf16x8*>(&dst[b]) = o;
    }
}

// ------------------------------------------------- main path (bf16, m97-style)
// Stage one [128 x 32] bf16 tile (8 KB) into linear LDS via global_load_lds.
// Wave stages 2 chunks of 1024 B (lane's 16 B lands at chunk base + lane*16).
__device__ __forceinline__ void stage32(const __bf16* __restrict__ src, int row0, int k0,
                                        __bf16* __restrict__ lds, int wave, int lane)
{
#pragma unroll
    for (int i = 0; i < 2; ++i) {
        const int chunk = wave * 2 + i;            // 0..7, each 1024 B = 16 rows
        const int elem  = chunk * 512 + lane * 8;  // element offset in tile
        const int r = elem >> 5, c = elem & 31;
        gload_lds16(&src[(size_t)(row0 + r) * H_N + k0 + c], &lds[chunk * 512]);
    }
}

__device__ __forceinline__ void gemm_bf16(const __bf16* __restrict__ A, const __bf16* __restrict__ W,
                                          int m0, int n0,
                                          __bf16* __restrict__ Asm, __bf16* __restrict__ Wsm,
                                          int wave, int lane, int wr, int wc, int l15, int lk,
                                          f32x4 acc[4][4])
{
    for (int k0 = 0; k0 < H_N; k0 += BKt) {
        stage32(A, m0, k0, Asm, wave, lane);
        stage32(W, n0, k0, Wsm, wave, lane);
        __syncthreads();
        bf16x8 af[4], bfr[4];
#pragma unroll
        for (int i = 0; i < 4; ++i)
            af[i] = *reinterpret_cast<const bf16x8*>(&Asm[(wr + i * 16 + l15) * BKt + lk]);
#pragma unroll
        for (int j = 0; j < 4; ++j)
            bfr[j] = *reinterpret_cast<const bf16x8*>(&Wsm[(wc + j * 16 + l15) * BKt + lk]);
#pragma unroll
        for (int i = 0; i < 4; ++i)
#pragma unroll
            for (int j = 0; j < 4; ++j)
                acc[i][j] = __builtin_amdgcn_mfma_f32_16x16x32_bf16(af[i], bfr[j], acc[i][j], 0, 0, 0);
        __syncthreads();
    }
}

__global__ __launch_bounds__(256)
void flcs_stageA2(const __bf16* __restrict__ sInB, const __bf16* __restrict__ sWB,
                  const __bf16* __restrict__ tInB, const __bf16* __restrict__ tWB,
                  const float* __restrict__ sB,  const float* __restrict__ tB,
                  const int* __restrict__ labels,
                  float* __restrict__ pMax, float* __restrict__ pSe,
                  float* __restrict__ pDot, float* __restrict__ pS2,
                  float* __restrict__ pT2,  float* __restrict__ sLab)
{
    __shared__ __bf16 Asm[BMt * BKt];
    __shared__ __bf16 Wsm[BNt * BKt];

    const int tid  = threadIdx.x;
    const int lane = tid & 63;
    const int wave = tid >> 6;
    const int wr   = (wave >> 1) * 64;
    const int wc   = (wave & 1) * 64;
    const int l15  = lane & 15;
    const int lsub = lane >> 4;
    const int lk   = lsub * 8;
    const int m0   = blockIdx.x * BMt;
    const int n0   = blockIdx.y * BNt;

    f32x4 accS[4][4], accT[4][4];
    const f32x4 fz = {0.f, 0.f, 0.f, 0.f};
#pragma unroll
    for (int i = 0; i < 4; ++i)
#pragma unroll
        for (int j = 0; j < 4; ++j) { accS[i][j] = fz; accT[i][j] = fz; }

    gemm_bf16(sInB, sWB, m0, n0, Asm, Wsm, wave, lane, wr, wc, l15, lk, accS);
    gemm_bf16(tInB, tWB, m0, n0, Asm, Wsm, wave, lane, wr, wc, l15, lk, accT);

    // --- epilogue: per-row stats over this wave's 64 columns ---
    float sb[4], tb[4];
#pragma unroll
    for (int n = 0; n < 4; ++n) {
        sb[n] = sB[n0 + wc + n * 16 + l15];
        tb[n] = tB[n0 + wc + n * 16 + l15];
    }
    const int gcb = blockIdx.y * 2 + (wc >> 6);

#pragma unroll
    for (int i = 0; i < 4; ++i) {
#pragma unroll
        for (int q = 0; q < 4; ++q) {
            float s[4], t[4];
#pragma unroll
            for (int n = 0; n < 4; ++n) {
                s[n] = accS[i][n][q] + sb[n];
                t[n] = accT[i][n][q] + tb[n];
            }
            float mx = fmaxf(fmaxf(s[0], s[1]), fmaxf(s[2], s[3]));
#pragma unroll
            for (int d = 1; d <= 8; d <<= 1) mx = fmaxf(mx, __shfl_xor(mx, d));
            float se = 0.f, dot = 0.f, s2 = 0.f, t2 = 0.f;
#pragma unroll
            for (int n = 0; n < 4; ++n) {
                se  += __expf(s[n] - mx);
                dot += s[n] * t[n];
                s2  += s[n] * s[n];
                t2  += t[n] * t[n];
            }
#pragma unroll
            for (int d = 1; d <= 8; d <<= 1) {
                se  += __shfl_xor(se, d);
                dot += __shfl_xor(dot, d);
                s2  += __shfl_xor(s2, d);
                t2  += __shfl_xor(t2, d);
            }
            const int grow = m0 + wr + i * 16 + lsub * 4 + q;
            if (l15 == 0) {
                const size_t p = (size_t)grow * NPART + gcb;
                pMax[p] = mx; pSe[p] = se; pDot[p] = dot; pS2[p] = s2; pT2[p] = t2;
            }
            const int lab = labels[grow];
            const int rel = lab - (n0 + wc);
            if (rel >= 0 && rel < 64) {
#pragma unroll
                for (int n = 0; n < 4; ++n)
                    if (rel == n * 16 + l15) sLab[grow] = s[n];
            }
        }
    }
}

// ------------------------------------------------- fallback path (round-1, fp32 in)
__device__ __forceinline__ void stage_tile(const float* __restrict__ src, int row0, int k0,
                                           __bf16* __restrict__ dst, int tid)
{
    int r = tid >> 3;
    const int c = (tid & 7) << 2;
#pragma unroll
    for (int it = 0; it < 4; ++it, r += 32) {
        const float4 v = *reinterpret_cast<const float4*>(&src[(size_t)(row0 + r) * H_N + k0 + c]);
        bf16x4 p;
        p[0] = (__bf16)v.x; p[1] = (__bf16)v.y; p[2] = (__bf16)v.z; p[3] = (__bf16)v.w;
        *reinterpret_cast<bf16x4*>(&dst[r * BKS + c]) = p;
    }
}

__device__ __forceinline__ void gemm_bt(const float* __restrict__ A, const float* __restrict__ W,
                                        int m0, int n0,
                                        __bf16* __restrict__ Asm, __bf16* __restrict__ Wsm,
                                        int tid, int wr, int wc, int l15, int lk,
                                        f32x4 acc[4][4])
{
    for (int k0 = 0; k0 < H_N; k0 += BKt) {
        stage_tile(A, m0, k0, Asm, tid);
        stage_tile(W, n0, k0, Wsm, tid);
        __syncthreads();
        bf16x8 af[4], bfr[4];
#pragma unroll
        for (int i = 0; i < 4; ++i)
            af[i] = *reinterpret_cast<const bf16x8*>(&Asm[(wr + i * 16 + l15) * BKS + lk]);
#pragma unroll
        for (int j = 0; j < 4; ++j)
            bfr[j] = *reinterpret_cast<const bf16x8*>(&Wsm[(wc + j * 16 + l15) * BKS + lk]);
#pragma unroll
        for (int i = 0; i < 4; ++i)
#pragma unroll
            for (int j = 0; j < 4; ++j)
                acc[i][j] = __builtin_amdgcn_mfma_f32_16x16x32_bf16(af[i], bfr[j], acc[i][j], 0, 0, 0);
        __syncthreads();
    }
}

__global__ __launch_bounds__(256)
void flcs_stageA(const float* __restrict__ sIn, const float* __restrict__ sW,
                 const float* __restrict__ tIn, const float* __restrict__ tW,
                 const float* __restrict__ sB,  const float* __restrict__ tB,
                 const int* __restrict__ labels,
                 float* __restrict__ pMax, float* __restrict__ pSe,
                 float* __restrict__ pDot, float* __restrict__ pS2,
                 float* __restrict__ pT2,  float* __restrict__ sLab)
{
    __shared__ __bf16 Asm[BMt * BKS];
    __shared__ __bf16 Wsm[BNt * BKS];

    const int tid  = threadIdx.x;
    const int lane = tid & 63;
    const int wave = tid >> 6;
    const int wr   = (wave >> 1) * 64;
    const int wc   = (wave & 1) * 64;
    const int l15  = lane & 15;
    const int lsub = lane >> 4;
    const int lk   = lsub * 8;
    const int m0   = blockIdx.x * BMt;
    const int n0   = blockIdx.y * BNt;

    f32x4 accS[4][4], accT[4][4];
    const f32x4 fz = {0.f, 0.f, 0.f, 0.f};
#pragma unroll
    for (int i = 0; i < 4; ++i)
#pragma unroll
        for (int j = 0; j < 4; ++j) { accS[i][j] = fz; accT[i][j] = fz; }

    gemm_bt(sIn, sW, m0, n0, Asm, Wsm, tid, wr, wc, l15, lk, accS);
    gemm_bt(tIn, tW, m0, n0, Asm, Wsm, tid, wr, wc, l15, lk, accT);

    float sb[4], tb[4];
#pragma unroll
    for (int n = 0; n < 4; ++n) {
        sb[n] = sB[n0 + wc + n * 16 + l15];
        tb[n] = tB[n0 + wc + n * 16 + l15];
    }
    const int gcb = blockIdx.y * 2 + (wc >> 6);

#pragma unroll
    for (int i = 0; i < 4; ++i) {
#pragma unroll
        for (int q = 0; q < 4; ++q) {
            float s[4], t[4];
#pragma unroll
            for (int n = 0; n < 4; ++n) {
                s[n] = accS[i][n][q] + sb[n];
                t[n] = accT[i][n][q] + tb[n];
            }
            float mx = fmaxf(fmaxf(s[0], s[1]), fmaxf(s[2], s[3]));
#pragma unroll
            for (int d = 1; d <= 8; d <<= 1) mx = fmaxf(mx, __shfl_xor(mx, d));
            float se = 0.f, dot = 0.f, s2 = 0.f, t2 = 0.f;
#pragma unroll
            for (int n = 0; n < 4; ++n) {
                se  += __expf(s[n] - mx);
                dot += s[n] * t[n];
                s2  += s[n] * s[n];
                t2  += t[n] * t[n];
            }
#pragma unroll
            for (int d = 1; d <= 8; d <<= 1) {
                se  += __shfl_xor(se, d);
                dot += __shfl_xor(dot, d);
                s2  += __shfl_xor(s2, d);
                t2  += __shfl_xor(t2, d);
            }
            const int grow = m0 + wr + i * 16 + lsub * 4 + q;
            if (l15 == 0) {
                const size_t p = (size_t)grow * NPART + gcb;
                pMax[p] = mx; pSe[p] = se; pDot[p] = dot; pS2[p] = s2; pT2[p] = t2;
            }
            const int lab = labels[grow];
            const int rel = lab - (n0 + wc);
            if (rel >= 0 && rel < 64) {
#pragma unroll
                for (int n = 0; n < 4; ++n)
                    if (rel == n * 16 + l15) sLab[grow] = s[n];
            }
        }
    }
}

// ------------------------------------------------- stage B / C (unchanged)
__global__ __launch_bounds__(256)
void flcs_stageB(const float* __restrict__ pMax, const float* __restrict__ pSe,
                 const float* __restrict__ pDot, const float* __restrict__ pS2,
                 const float* __restrict__ pT2,  const float* __restrict__ sLab,
                 float* __restrict__ rowNll, float* __restrict__ rowSoft)
{
    const int lane = threadIdx.x & 63;
    const int row  = blockIdx.x * 4 + (threadIdx.x >> 6);
    const size_t base = (size_t)row * NPART;

    float mx = -INFINITY;
    for (int i = lane; i < NPART; i += 64) mx = fmaxf(mx, pMax[base + i]);
#pragma unroll
    for (int d = 1; d <= 32; d <<= 1) mx = fmaxf(mx, __shfl_xor(mx, d));

    float se = 0.f, dot = 0.f, s2 = 0.f, t2 = 0.f;
    for (int i = lane; i < NPART; i += 64) {
        se  += pSe[base + i] * __expf(pMax[base + i] - mx);
        dot += pDot[base + i];
        s2  += pS2[base + i];
        t2  += pT2[base + i];
    }
#pragma unroll
    for (int d = 1; d <= 32; d <<= 1) {
        se  += __shfl_xor(se, d);
        dot += __shfl_xor(dot, d);
        s2  += __shfl_xor(s2, d);
        t2  += __shfl_xor(t2, d);
    }
    if (lane == 0) {
        const float lse = mx + logf(se);
        rowNll[row] = lse - sLab[row];
        const float ns = fmaxf(sqrtf(s2), 1e-12f);
        const float nt = fmaxf(sqrtf(t2), 1e-12f);
        rowSoft[row] = 0.5f * (1.f - dot / (ns * nt));
    }
}

__global__ __launch_bounds__(256)
void flcs_stageC(const float* __restrict__ rowNll, const float* __restrict__ rowSoft,
                 const int* __restrict__ labels, float* __restrict__ out)
{
    const int tid = threadIdx.x;
    float nll = 0.f, soft = 0.f, nv = 0.f;
    for (int i = tid; i < BT_N; i += 256) {
        if (labels[i] != IGNORE_INDEX) { nll += rowNll[i]; nv += 1.f; }
        soft += rowSoft[i];
    }
#pragma unroll
    for (int d = 1; d <= 32; d <<= 1) {
        nll  += __shfl_xor(nll, d);
        soft += __shfl_xor(soft, d);
        nv   += __shfl_xor(nv, d);
    }
    __shared__ float rN[4], rS[4], rV[4];
    const int w = tid >> 6;
    if ((tid & 63) == 0) { rN[w] = nll; rS[w] = soft; rV[w] = nv; }
    __syncthreads();
    if (tid == 0) {
        float N = 0.f, S = 0.f, Vv = 0.f;
        for (int k = 0; k < 4; ++k) { N += rN[k]; S += rS[k]; Vv += rV[k]; }
        out[0] = 0.5f * (N / fmaxf(Vv, 1.f)) + 0.5f * (S / (float)BT_N);
    }
}

extern "C" void kernel_launch(void* const* d_in, const int* in_sizes, int n_in,
                              void* d_out, int out_size, void* d_ws, size_t ws_size,
                              hipStream_t stream)
{
    const float* sIn    = (const float*)d_in[0];
    const float* sW     = (const float*)d_in[1];
    const float* tIn    = (const float*)d_in[2];
    const float* tW     = (const float*)d_in[3];
    const int*   labels = (const int*)d_in[4];
    const float* sB     = (const float*)d_in[5];
    const float* tB     = (const float*)d_in[6];
    float* out = (float*)d_out;

    const size_t np = (size_t)BT_N * NPART;
    float* pMax = (float*)d_ws;
    float* pSe  = pMax + np;
    float* pDot = pSe  + np;
    float* pS2  = pDot + np;
    float* pT2  = pS2  + np;
    float* sLab = pT2  + np;
    float* rowNll  = sLab + BT_N;
    float* rowSoft = rowNll + BT_N;

    size_t off = (size_t)((char*)(rowSoft + BT_N) - (char*)d_ws);
    off = (off + 255) & ~(size_t)255;
    const size_t nIn = (size_t)BT_N * H_N;   // 4,194,304
    const size_t nW  = (size_t)V_N * H_N;    // 65,536,000
    __bf16* sInB = (__bf16*)((char*)d_ws + off);
    __bf16* tInB = sInB + nIn;
    __bf16* sWB  = tInB + nIn;
    __bf16* tWB  = sWB + nW;
    const size_t need = off + 2 * (nIn + nW) * sizeof(__bf16);

    if (ws_size >= need) {
        cast_f32_bf16<<<1024, 256, 0, stream>>>(sIn, sInB, (int)(nIn / 8));
        cast_f32_bf16<<<1024, 256, 0, stream>>>(tIn, tInB, (int)(nIn / 8));
        cast_f32_bf16<<<2048, 256, 0, stream>>>(sW,  sWB,  (int)(nW / 8));
        cast_f32_bf16<<<2048, 256, 0, stream>>>(tW,  tWB,  (int)(nW / 8));
        flcs_stageA2<<<dim3(BT_N / BMt, V_N / BNt), 256, 0, stream>>>(
            sInB, sWB, tInB, tWB, sB, tB, labels, pMax, pSe, pDot, pS2, pT2, sLab);
    } else {
        flcs_stageA<<<dim3(BT_N / BMt, V_N / BNt), 256, 0, stream>>>(
            sIn, sW, tIn, tW, sB, tB, labels, pMax, pSe, pDot, pS2, pT2, sLab);
    }
    flcs_stageB<<<BT_N / 4, 256, 0, stream>>>(pMax, pSe, pDot, pS2, pT2, sLab, rowNll, rowSoft);
    flcs_stageC<<<1, 256, 0, stream>>>(rowNll, rowSoft, labels, out);
}